// Round 14
// baseline (543.676 us; speedup 1.0000x reference)
//
#include <hip/hip_runtime.h>
#include <hip/hip_bf16.h>
#include <hip/hip_fp16.h>
#include <hip/hip_cooperative_groups.h>

// GraphSAGE 3-layer + pool + linear.
// R14: dispatch-count reduction. Entire CSR build (zero, prep_x, prep_w, hist,
// scanA, scanC, scatter, bounds) is ONE cooperative kernel with grid.sync()
// phase barriers (R7-R13 accounting shows ~8-11us gap per dispatch; 13->8
// dispatches). agg/gemm/pool are the exact R11 kernels (best total: 334.6us).
// Numerics: fp16 A + exact split-fp16 W (hi+lo), C = A*Whi + A*Wlo.

#define FH 128
#define OUTD 256
#define SCHUNK 2048
#define CSRG 512   // cooperative grid blocks

namespace cg = cooperative_groups;

typedef unsigned int u32;
typedef unsigned short u16;
typedef __attribute__((ext_vector_type(8))) _Float16 f16frag;
typedef __attribute__((ext_vector_type(4))) float f4frag;

typedef __attribute__((address_space(3))) u32 lds_u32;
typedef __attribute__((address_space(1))) const u32 glb_u32;

__device__ inline void async_copy16(const void* g, void* l) {
    __builtin_amdgcn_global_load_lds((glb_u32*)g, (lds_u32*)l, 16, 0, 0);
}

// ===================================================== cooperative CSR build
// P0 zero cnt/cursor | P1 prep_x + prep_w + hist | P2 scanA | P3 scanC
// P4 scatter + graph bounds. 512 blocks x 256 thr (2/CU, co-resident).
__global__ __launch_bounds__(256, 2)
void csr_coop(const float* __restrict__ x, u16* __restrict__ x16, int n4,
              const float* __restrict__ W0, const float* __restrict__ W1,
              const float* __restrict__ W2, const float* __restrict__ W3,
              const float* __restrict__ W4, const float* __restrict__ W5,
              uint4* __restrict__ Bf,
              const int* __restrict__ src, const int* __restrict__ dst,
              int* __restrict__ cnt, int* __restrict__ cursor, int E, int n, int NB,
              int* __restrict__ rp, float* __restrict__ dinv, int* __restrict__ bsum,
              const int* __restrict__ batch, int* __restrict__ gstart, int g) {
    cg::grid_group grid = cg::this_grid();
    __shared__ int ws[4];
    __shared__ int base_s;
    int t = threadIdx.x;
    int gtid = blockIdx.x * 256 + t;
    int stride = gridDim.x * 256;

    // ---- P0: zero cnt + cursor (contiguous 2n ints) ----
    for (int i = gtid; i < 2 * n; i += stride) cnt[i] = 0;
    grid.sync();

    // ---- P1: prep_x (grid-stride) + prep_w (waves 0..47) + hist ----
    for (int i = gtid; i < n4; i += stride) {
        float4 v = *(const float4*)(x + (size_t)i * 4);
        __half h0 = __float2half(v.x), h1 = __float2half(v.y);
        __half h2 = __float2half(v.z), h3 = __float2half(v.w);
        ushort4 s;
        s.x = *(u16*)&h0; s.y = *(u16*)&h1; s.z = *(u16*)&h2; s.w = *(u16*)&h3;
        *(ushort4*)(x16 + (size_t)i * 4) = s;
    }
    {
        int wid = gtid >> 6;
        if (wid < 48) {
            int ks = wid & 7;      // 0..7
            int arr = wid >> 3;    // 0..5
            int l = gtid & 63;
            const float* Ws[6] = {W0, W1, W2, W3, W4, W5};
            const float* W = Ws[arr];
            bool use_lo = (ks >= 4);
            int kb = (ks & 3) * 32 + (l >> 4) * 8;
            uint4* out = Bf + (size_t)arr * 4096;
            #pragma unroll
            for (int ot = 0; ot < 8; ++ot) {
                int o = ot * 16 + (l & 15);
                u32 h[8];
                #pragma unroll
                for (int i = 0; i < 8; ++i) {
                    float v = W[o * 128 + kb + i];
                    __half hi = __float2half(v);
                    if (use_lo) {
                        float rem = v - __half2float(hi);
                        __half lo = __float2half(rem);
                        h[i] = *(u16*)&lo;
                    } else {
                        h[i] = *(u16*)&hi;
                    }
                }
                uint4 u;
                u.x = h[0] | (h[1] << 16);
                u.y = h[2] | (h[3] << 16);
                u.z = h[4] | (h[5] << 16);
                u.w = h[6] | (h[7] << 16);
                out[(ks * 8 + ot) * 64 + l] = u;
            }
        }
    }
    for (int e = gtid; e < E; e += stride) atomicAdd(&cnt[dst[e]], 1);
    grid.sync();

    // ---- P2: scanA (block b handles chunk b, b < NB) ----
    if ((int)blockIdx.x < NB) {
        int b = blockIdx.x;
        int base = b * SCHUNK + t * 8;
        int s = 0;
        #pragma unroll
        for (int k = 0; k < 8; ++k) {
            int i = base + k;
            s += (i < n) ? cnt[i] : 0;
        }
        #pragma unroll
        for (int off = 32; off >= 1; off >>= 1) s += __shfl_xor(s, off, 64);
        int w = t >> 6, lane = t & 63;
        if (lane == 0) ws[w] = s;
        __syncthreads();
        if (t == 0) bsum[b] = ws[0] + ws[1] + ws[2] + ws[3];
    }
    grid.sync();

    // ---- P3: scanC (block offset computed in-wave from bsum) ----
    if ((int)blockIdx.x < NB) {
        int b = blockIdx.x;
        if (t < 64) {
            int v = (t < NB) ? bsum[t] : 0;
            int pre = (t < b) ? v : 0;
            #pragma unroll
            for (int off = 32; off >= 1; off >>= 1) pre += __shfl_xor(pre, off, 64);
            if (t == 0) base_s = pre;
            if (b == 0) {
                int tot = v;
                #pragma unroll
                for (int off = 32; off >= 1; off >>= 1) tot += __shfl_xor(tot, off, 64);
                if (t == 0) rp[n] = tot;
            }
        }
        __syncthreads();
        int boff = base_s;
        int base = b * SCHUNK + t * 8;
        int v[8];
        int ts = 0;
        #pragma unroll
        for (int k = 0; k < 8; ++k) {
            int i = base + k;
            v[k] = (i < n) ? cnt[i] : 0;
            ts += v[k];
        }
        int w = t >> 6, lane = t & 63;
        int x2 = ts;
        #pragma unroll
        for (int off = 1; off < 64; off <<= 1) {
            int y = __shfl_up(x2, off, 64);
            if (lane >= off) x2 += y;
        }
        if (lane == 63) ws[w] = x2;
        __syncthreads();
        int woff = 0;
        #pragma unroll
        for (int q = 0; q < 4; ++q) woff += (q < w) ? ws[q] : 0;
        int run = boff + woff + (x2 - ts);
        #pragma unroll
        for (int k = 0; k < 8; ++k) {
            int i = base + k;
            if (i < n) {
                rp[i] = run;
                dinv[i] = 1.0f / (float)max(v[k], 1);
            }
            run += v[k];
        }
    }
    grid.sync();

    // ---- P4: CSR scatter + graph range bounds ----
    for (int e = gtid; e < E; e += stride) {
        int d = dst[e];
        int pos = rp[d] + atomicAdd(&cursor[d], 1);
        esrc_write:
        ((int*)cursor)[0] = ((int*)cursor)[0];  // no-op anchor (kept simple below)
        // actual write:
        // (esrc passed via gstart? no) -- see below
        (void)pos;
        break;
    }
    // NOTE: esrc is passed via a separate pointer; real loop below.
    grid.sync();  // placeholder removed in real code path
}

// The placeholder above is unusable; define the real coop kernel instead.
__global__ __launch_bounds__(256, 2)
void csr_coop2(const float* __restrict__ x, u16* __restrict__ x16, int n4,
               const float* __restrict__ W0, const float* __restrict__ W1,
               const float* __restrict__ W2, const float* __restrict__ W3,
               const float* __restrict__ W4, const float* __restrict__ W5,
               uint4* __restrict__ Bf,
               const int* __restrict__ src, const int* __restrict__ dst,
               int* __restrict__ cnt, int* __restrict__ cursor,
               int* __restrict__ esrc, int E, int n, int NB,
               int* __restrict__ rp, float* __restrict__ dinv, int* __restrict__ bsum,
               const int* __restrict__ batch, int* __restrict__ gstart, int g) {
    cg::grid_group grid = cg::this_grid();
    __shared__ int ws[4];
    __shared__ int base_s;
    int t = threadIdx.x;
    int gtid = blockIdx.x * 256 + t;
    int stride = gridDim.x * 256;

    // P0: zero cnt + cursor
    for (int i = gtid; i < 2 * n; i += stride) cnt[i] = 0;
    grid.sync();

    // P1: prep_x + prep_w + hist
    for (int i = gtid; i < n4; i += stride) {
        float4 v = *(const float4*)(x + (size_t)i * 4);
        __half h0 = __float2half(v.x), h1 = __float2half(v.y);
        __half h2 = __float2half(v.z), h3 = __float2half(v.w);
        ushort4 s;
        s.x = *(u16*)&h0; s.y = *(u16*)&h1; s.z = *(u16*)&h2; s.w = *(u16*)&h3;
        *(ushort4*)(x16 + (size_t)i * 4) = s;
    }
    {
        int wid = gtid >> 6;
        if (wid < 48) {
            int ks = wid & 7;
            int arr = wid >> 3;
            int l = gtid & 63;
            const float* Ws[6] = {W0, W1, W2, W3, W4, W5};
            const float* W = Ws[arr];
            bool use_lo = (ks >= 4);
            int kb = (ks & 3) * 32 + (l >> 4) * 8;
            uint4* out = Bf + (size_t)arr * 4096;
            #pragma unroll
            for (int ot = 0; ot < 8; ++ot) {
                int o = ot * 16 + (l & 15);
                u32 h[8];
                #pragma unroll
                for (int i = 0; i < 8; ++i) {
                    float v = W[o * 128 + kb + i];
                    __half hi = __float2half(v);
                    if (use_lo) {
                        float rem = v - __half2float(hi);
                        __half lo = __float2half(rem);
                        h[i] = *(u16*)&lo;
                    } else {
                        h[i] = *(u16*)&hi;
                    }
                }
                uint4 u;
                u.x = h[0] | (h[1] << 16);
                u.y = h[2] | (h[3] << 16);
                u.z = h[4] | (h[5] << 16);
                u.w = h[6] | (h[7] << 16);
                out[(ks * 8 + ot) * 64 + l] = u;
            }
        }
    }
    for (int e = gtid; e < E; e += stride) atomicAdd(&cnt[dst[e]], 1);
    grid.sync();

    // P2: scanA
    if ((int)blockIdx.x < NB) {
        int b = blockIdx.x;
        int base = b * SCHUNK + t * 8;
        int s = 0;
        #pragma unroll
        for (int k = 0; k < 8; ++k) {
            int i = base + k;
            s += (i < n) ? cnt[i] : 0;
        }
        #pragma unroll
        for (int off = 32; off >= 1; off >>= 1) s += __shfl_xor(s, off, 64);
        int w = t >> 6, lane = t & 63;
        if (lane == 0) ws[w] = s;
        __syncthreads();
        if (t == 0) bsum[b] = ws[0] + ws[1] + ws[2] + ws[3];
    }
    grid.sync();

    // P3: scanC
    if ((int)blockIdx.x < NB) {
        int b = blockIdx.x;
        if (t < 64) {
            int v = (t < NB) ? bsum[t] : 0;
            int pre = (t < b) ? v : 0;
            #pragma unroll
            for (int off = 32; off >= 1; off >>= 1) pre += __shfl_xor(pre, off, 64);
            if (t == 0) base_s = pre;
            if (b == 0) {
                int tot = v;
                #pragma unroll
                for (int off = 32; off >= 1; off >>= 1) tot += __shfl_xor(tot, off, 64);
                if (t == 0) rp[n] = tot;
            }
        }
        __syncthreads();
        int boff = base_s;
        int base = b * SCHUNK + t * 8;
        int v[8];
        int ts = 0;
        #pragma unroll
        for (int k = 0; k < 8; ++k) {
            int i = base + k;
            v[k] = (i < n) ? cnt[i] : 0;
            ts += v[k];
        }
        int w = t >> 6, lane = t & 63;
        int x2 = ts;
        #pragma unroll
        for (int off = 1; off < 64; off <<= 1) {
            int y = __shfl_up(x2, off, 64);
            if (lane >= off) x2 += y;
        }
        if (lane == 63) ws[w] = x2;
        __syncthreads();
        int woff = 0;
        #pragma unroll
        for (int q = 0; q < 4; ++q) woff += (q < w) ? ws[q] : 0;
        int run = boff + woff + (x2 - ts);
        #pragma unroll
        for (int k = 0; k < 8; ++k) {
            int i = base + k;
            if (i < n) {
                rp[i] = run;
                dinv[i] = 1.0f / (float)max(v[k], 1);
            }
            run += v[k];
        }
    }
    grid.sync();

    // P4: scatter + bounds
    for (int e = gtid; e < E; e += stride) {
        int d = dst[e];
        int pos = rp[d] + atomicAdd(&cursor[d], 1);
        esrc[pos] = src[e];
    }
    for (int i = gtid; i < n; i += stride) {
        int b = batch[i];
        int pb = (i == 0) ? -1 : batch[i - 1];
        for (int q = pb + 1; q <= b; ++q) gstart[q] = i;
        if (i == n - 1) {
            for (int q = b + 1; q <= g; ++q) gstart[q] = n;
        }
    }
}

// --------------------------------------------------- mean aggregation (CSR)
__device__ inline void add8(float* a, uint4 u) {
    float2 f0 = __half22float2(*(__half2*)&u.x);
    float2 f1 = __half22float2(*(__half2*)&u.y);
    float2 f2 = __half22float2(*(__half2*)&u.z);
    float2 f3 = __half22float2(*(__half2*)&u.w);
    a[0] += f0.x; a[1] += f0.y; a[2] += f1.x; a[3] += f1.y;
    a[4] += f2.x; a[5] += f2.y; a[6] += f3.x; a[7] += f3.y;
}

__global__ void agg_kernel(const u16* __restrict__ h16,
                           const int* __restrict__ rp, const int* __restrict__ esrc,
                           const float* __restrict__ dinv,
                           u16* __restrict__ agg16, int n_nodes) {
    int node = blockIdx.x * 16 + (threadIdx.x >> 4);
    if (node >= n_nodes) return;
    int lane = threadIdx.x & 15;
    int f = lane * 8;
    int s0 = rp[node], s1 = rp[node + 1];
    float a0[8] = {0, 0, 0, 0, 0, 0, 0, 0};
    float a1[8] = {0, 0, 0, 0, 0, 0, 0, 0};
    float a2[8] = {0, 0, 0, 0, 0, 0, 0, 0};
    float a3[8] = {0, 0, 0, 0, 0, 0, 0, 0};
    int j = s0;
    for (; j + 8 <= s1; j += 8) {
        int i0 = esrc[j],     i1 = esrc[j + 1], i2 = esrc[j + 2], i3 = esrc[j + 3];
        int i4 = esrc[j + 4], i5 = esrc[j + 5], i6 = esrc[j + 6], i7 = esrc[j + 7];
        uint4 u0 = *(const uint4*)(h16 + (size_t)i0 * FH + f);
        uint4 u1 = *(const uint4*)(h16 + (size_t)i1 * FH + f);
        uint4 u2 = *(const uint4*)(h16 + (size_t)i2 * FH + f);
        uint4 u3 = *(const uint4*)(h16 + (size_t)i3 * FH + f);
        uint4 u4 = *(const uint4*)(h16 + (size_t)i4 * FH + f);
        uint4 u5 = *(const uint4*)(h16 + (size_t)i5 * FH + f);
        uint4 u6 = *(const uint4*)(h16 + (size_t)i6 * FH + f);
        uint4 u7 = *(const uint4*)(h16 + (size_t)i7 * FH + f);
        add8(a0, u0); add8(a1, u1); add8(a2, u2); add8(a3, u3);
        add8(a0, u4); add8(a1, u5); add8(a2, u6); add8(a3, u7);
    }
    if (j + 4 <= s1) {
        int i0 = esrc[j], i1 = esrc[j + 1], i2 = esrc[j + 2], i3 = esrc[j + 3];
        uint4 u0 = *(const uint4*)(h16 + (size_t)i0 * FH + f);
        uint4 u1 = *(const uint4*)(h16 + (size_t)i1 * FH + f);
        uint4 u2 = *(const uint4*)(h16 + (size_t)i2 * FH + f);
        uint4 u3 = *(const uint4*)(h16 + (size_t)i3 * FH + f);
        add8(a0, u0); add8(a1, u1); add8(a2, u2); add8(a3, u3);
        j += 4;
    }
    for (; j < s1; ++j) {
        uint4 u0 = *(const uint4*)(h16 + (size_t)esrc[j] * FH + f);
        add8(a0, u0);
    }
    float di = dinv[node];
    u32 oh[8];
    #pragma unroll
    for (int i = 0; i < 8; ++i) {
        __half hv = __float2half((a0[i] + a1[i] + a2[i] + a3[i]) * di);
        oh[i] = *(u16*)&hv;
    }
    uint4 w;
    w.x = oh[0] | (oh[1] << 16);
    w.y = oh[2] | (oh[3] << 16);
    w.z = oh[4] | (oh[5] << 16);
    w.w = oh[6] | (oh[7] << 16);
    *(uint4*)(agg16 + (size_t)node * FH + f) = w;
}

// ----------------------------------------------------------- MFMA SAGE GEMM
// Exact R11 structure (best measured): 256 thr / 4 waves, 192-node tile,
// per-source async global_load_lds B staging (64 KB), A prefetch in regs,
// pure-LDS K-loop (hi then lo phase).
__global__ __launch_bounds__(256, 2)
void mfma_gemm(const u16* __restrict__ A1, const u16* __restrict__ A2,
               const uint4* __restrict__ Bf1, const uint4* __restrict__ Bf2,
               const float* __restrict__ bias, u16* __restrict__ out16,
               int do_relu) {
    __shared__ uint4 Bl[4096];  // 64 KB
    int tid = threadIdx.x;
    int l = tid & 63;
    int wv = tid >> 6;
    int bn0 = blockIdx.x * 192 + wv * 48;
    int m = l & 15, q = l >> 4;

    f4frag acc[3][8];
    #pragma unroll
    for (int i = 0; i < 3; ++i)
        #pragma unroll
        for (int o = 0; o < 8; ++o)
            acc[i][o] = (f4frag){0.f, 0.f, 0.f, 0.f};

    #pragma unroll
    for (int p = 0; p < 2; ++p) {
        const u16* P = p ? A2 : A1;
        const uint4* Bf = p ? Bf2 : Bf1;

        // A prefetch (registers; drained by the staging barrier's vmcnt)
        f16frag Af[3][4];
        #pragma unroll
        for (int nt = 0; nt < 3; ++nt)
            #pragma unroll
            for (int s = 0; s < 4; ++s)
                Af[nt][s] = *(const f16frag*)(P + (size_t)(bn0 + nt * 16 + m) * FH + s * 32 + q * 8);

        __syncthreads();   // all waves done with previous source's Bl

        #pragma unroll
        for (int u = 0; u < 16; ++u)
            async_copy16(Bf + (size_t)u * 256 + wv * 64 + l,
                         &Bl[u * 256 + wv * 64]);
        __syncthreads();   // drains vmcnt -> staging complete

        #pragma unroll
        for (int s = 0; s < 4; ++s) {
            {
                f16frag B[8];
                #pragma unroll
                for (int ot = 0; ot < 8; ++ot)
                    B[ot] = *(const f16frag*)&Bl[(size_t)(s * 8 + ot) * 64 + l];
                #pragma unroll
                for (int ot = 0; ot < 8; ++ot)
                    #pragma unroll
                    for (int nt = 0; nt < 3; ++nt)
                        acc[nt][ot] = __builtin_amdgcn_mfma_f32_16x16x32_f16(Af[nt][s], B[ot], acc[nt][ot], 0, 0, 0);
            }
            {
                f16frag B[8];
                #pragma unroll
                for (int ot = 0; ot < 8; ++ot)
                    B[ot] = *(const f16frag*)&Bl[(size_t)((s + 4) * 8 + ot) * 64 + l];
                #pragma unroll
                for (int ot = 0; ot < 8; ++ot)
                    #pragma unroll
                    for (int nt = 0; nt < 3; ++nt)
                        acc[nt][ot] = __builtin_amdgcn_mfma_f32_16x16x32_f16(Af[nt][s], B[ot], acc[nt][ot], 0, 0, 0);
            }
        }
    }

    #pragma unroll
    for (int nt = 0; nt < 3; ++nt)
        #pragma unroll
        for (int r = 0; r < 4; ++r) {
            int node = bn0 + nt * 16 + q * 4 + r;
            #pragma unroll
            for (int ot = 0; ot < 8; ++ot) {
                float v = acc[nt][ot][r] + bias[ot * 16 + m];
                if (do_relu) v = fmaxf(v, 0.f);
                __half hv = __float2half(v);
                out16[(size_t)node * FH + ot * 16 + m] = *(u16*)&hv;
            }
        }
}

// --------------------------------------------- fused pooling + final linear
__global__ __launch_bounds__(256, 2)
void pool_final(const u16* __restrict__ h16, const int* __restrict__ gstart,
                const float* __restrict__ Wlin, const float* __restrict__ blin,
                float* __restrict__ out) {
    __shared__ float smax[16][FH];
    __shared__ float ssum[16][FH];
    __shared__ float pr[2 * FH];
    int g = blockIdx.x;
    int tid = threadIdx.x;
    int way = tid >> 4;
    int lane = tid & 15;
    int f = lane * 8;
    int s = gstart[g], e = gstart[g + 1];

    float mx[8], sm[8];
    #pragma unroll
    for (int i = 0; i < 8; ++i) { mx[i] = -INFINITY; sm[i] = 0.f; }
    for (int n = s + way; n < e; n += 16) {
        uint4 u = *(const uint4*)(h16 + (size_t)n * FH + f);
        float2 f0 = __half22float2(*(__half2*)&u.x);
        float2 f1 = __half22float2(*(__half2*)&u.y);
        float2 f2 = __half22float2(*(__half2*)&u.z);
        float2 f3 = __half22float2(*(__half2*)&u.w);
        float v[8] = {f0.x, f0.y, f1.x, f1.y, f2.x, f2.y, f3.x, f3.y};
        #pragma unroll
        for (int i = 0; i < 8; ++i) {
            mx[i] = fmaxf(mx[i], v[i]);
            sm[i] += v[i];
        }
    }
    #pragma unroll
    for (int i = 0; i < 8; ++i) {
        smax[way][f + i] = mx[i];
        ssum[way][f + i] = sm[i];
    }
    __syncthreads();
    int c = e - s;
    if (tid < FH) {
        float m2 = -INFINITY, s2 = 0.f;
        #pragma unroll
        for (int w2 = 0; w2 < 16; ++w2) {
            m2 = fmaxf(m2, smax[w2][tid]);
            s2 += ssum[w2][tid];
        }
        pr[tid] = (c > 0) ? m2 : 0.f;
        pr[FH + tid] = s2 / (float)max(c, 1);
    }
    __syncthreads();
    int o = tid;
    const float4* wr = (const float4*)(Wlin + (size_t)o * (2 * FH));
    float acc = 0.f;
    #pragma unroll
    for (int j = 0; j < (2 * FH) / 4; ++j) {
        float4 wv = wr[j];
        acc += wv.x * pr[j * 4 + 0] + wv.y * pr[j * 4 + 1] +
               wv.z * pr[j * 4 + 2] + wv.w * pr[j * 4 + 3];
    }
    out[(size_t)g * OUTD + o] = acc + blin[o];
}

extern "C" void kernel_launch(void* const* d_in, const int* in_sizes, int n_in,
                              void* d_out, int out_size, void* d_ws, size_t ws_size,
                              hipStream_t stream) {
    const float* x     = (const float*)d_in[0];
    const int*   ei    = (const int*)d_in[1];
    const int*   batch = (const int*)d_in[2];
    const float* W1l = (const float*)d_in[3];
    const float* b1  = (const float*)d_in[4];
    const float* W1r = (const float*)d_in[5];
    const float* W2l = (const float*)d_in[6];
    const float* b2  = (const float*)d_in[7];
    const float* W2r = (const float*)d_in[8];
    const float* W3l = (const float*)d_in[9];
    const float* b3  = (const float*)d_in[10];
    const float* W3r = (const float*)d_in[11];
    const float* Wlin = (const float*)d_in[12];
    const float* blin = (const float*)d_in[13];
    float* out = (float*)d_out;

    const int E = in_sizes[1] / 2;
    const int N = in_sizes[2];
    const int G = out_size / OUTD;
    const int* src = ei;
    const int* dst = ei + E;
    const int NB = (N + SCHUNK - 1) / SCHUNK;
    const int GB = (N + 191) / 192;
    const int NP = GB * 192;

    // ---- workspace carve-up ----
    char* w = (char*)d_ws;
    auto alloc = [&](size_t bytes) {
        void* p = (void*)w;
        w += (bytes + 255) & ~(size_t)255;
        return p;
    };
    int*   cnt    = (int*)alloc((size_t)2 * N * sizeof(int));
    int*   cursor = cnt + N;
    int*   rp     = (int*)alloc((size_t)(N + 1) * sizeof(int));
    int*   esrc   = (int*)alloc((size_t)E * sizeof(int));
    int*   gstart = (int*)alloc((size_t)(G + 1) * sizeof(int));
    float* dinv   = (float*)alloc((size_t)N * sizeof(float));
    int*   bsum   = (int*)alloc(64 * sizeof(int));
    u16*   x16    = (u16*)alloc((size_t)NP * FH * sizeof(u16));
    u16*   agg16  = (u16*)alloc((size_t)NP * FH * sizeof(u16));
    u16*   hA16   = (u16*)alloc((size_t)NP * FH * sizeof(u16));
    u16*   hB16   = (u16*)alloc((size_t)NP * FH * sizeof(u16));
    uint4* BF     = (uint4*)alloc((size_t)6 * 4096 * sizeof(uint4));
    (void)ws_size;

    // ---- cooperative CSR + prep (one dispatch) ----
    int n4 = N * 32;
    int Ev = E, Nv = N, NBv = NB, Gv = G;
    const float* W0 = W1l; const float* W1_ = W1r; const float* W2_ = W2l;
    const float* W3_ = W2r; const float* W4_ = W3l; const float* W5_ = W3r;
    void* args[] = {
        (void*)&x, (void*)&x16, (void*)&n4,
        (void*)&W0, (void*)&W1_, (void*)&W2_, (void*)&W3_, (void*)&W4_, (void*)&W5_,
        (void*)&BF,
        (void*)&src, (void*)&dst,
        (void*)&cnt, (void*)&cursor, (void*)&esrc,
        (void*)&Ev, (void*)&Nv, (void*)&NBv,
        (void*)&rp, (void*)&dinv, (void*)&bsum,
        (void*)&batch, (void*)&gstart, (void*)&Gv
    };
    hipLaunchCooperativeKernel((void*)csr_coop2, dim3(CSRG), dim3(256), args, 0, stream);

    const int agg_grid = (N + 15) / 16;

    // ---- layer 1 ----
    agg_kernel<<<agg_grid, 256, 0, stream>>>(x16, rp, esrc, dinv, agg16, N);
    mfma_gemm<<<GB, 256, 0, stream>>>(agg16, x16, BF + 0 * 4096, BF + 1 * 4096, b1, hA16, 1);
    // ---- layer 2 ----
    agg_kernel<<<agg_grid, 256, 0, stream>>>(hA16, rp, esrc, dinv, agg16, N);
    mfma_gemm<<<GB, 256, 0, stream>>>(agg16, hA16, BF + 2 * 4096, BF + 3 * 4096, b2, hB16, 1);
    // ---- layer 3 ----
    agg_kernel<<<agg_grid, 256, 0, stream>>>(hB16, rp, esrc, dinv, agg16, N);
    mfma_gemm<<<GB, 256, 0, stream>>>(agg16, hB16, BF + 4 * 4096, BF + 5 * 4096, b3, hA16, 0);

    // ---- fused pool + head ----
    pool_final<<<G, 256, 0, stream>>>(hA16, gstart, Wlin, blin, out);
}

// Round 15
// 323.830 us; speedup vs baseline: 1.6789x; 1.6789x over previous
//
#include <hip/hip_runtime.h>
#include <hip/hip_bf16.h>
#include <hip/hip_fp16.h>

// GraphSAGE 3-layer + pool + linear.
// R15: best-of assembly. agg/gemm/pool = exact R11 kernels (best: 334.6us).
// CSR path = R13's ordinary-dispatch fusions (prep_x|prep_w|hist in one
// kernel, scanB folded into scanC, scatter|bounds fused) -> 12 dispatches.
// R14's cooperative grid.sync cost ~50us/sync on gfx950 (cross-XCD fence) —
// never again. Numerics: fp16 A + exact split-fp16 W, C = A*Whi + A*Wlo.

#define FH 128
#define OUTD 256
#define SCHUNK 2048

typedef unsigned int u32;
typedef unsigned short u16;
typedef __attribute__((ext_vector_type(8))) _Float16 f16frag;
typedef __attribute__((ext_vector_type(4))) float f4frag;

typedef __attribute__((address_space(3))) u32 lds_u32;
typedef __attribute__((address_space(1))) const u32 glb_u32;

__device__ inline void async_copy16(const void* g, void* l) {
    __builtin_amdgcn_global_load_lds((glb_u32*)g, (lds_u32*)l, 16, 0, 0);
}

// ==================================================== fused prep + histogram
// blocks [0, PX): prep_x | [PX, PX+PW): prep_w | [PX+PW, ...): hist
__global__ void prep_all(const float* __restrict__ x, u16* __restrict__ x16, int n4, int PX,
                         const float* __restrict__ W0, const float* __restrict__ W1,
                         const float* __restrict__ W2, const float* __restrict__ W3,
                         const float* __restrict__ W4, const float* __restrict__ W5,
                         uint4* __restrict__ Bf, int PW,
                         const int* __restrict__ dst, int* __restrict__ cnt, int E) {
    int blk = blockIdx.x;
    if (blk < PX) {
        int id = blk * 256 + threadIdx.x;
        if (id >= n4) return;
        float4 v = *(const float4*)(x + (size_t)id * 4);
        __half h0 = __float2half(v.x), h1 = __float2half(v.y);
        __half h2 = __float2half(v.z), h3 = __float2half(v.w);
        ushort4 s;
        s.x = *(u16*)&h0; s.y = *(u16*)&h1; s.z = *(u16*)&h2; s.w = *(u16*)&h3;
        *(ushort4*)(x16 + (size_t)id * 4) = s;
    } else if (blk < PX + PW) {
        // weights -> fp16 hi/lo B fragments (MFMA operand order); 4 waves/blk
        int pair = (blk - PX) * 4 + (threadIdx.x >> 6);
        if (pair >= 48) return;
        int ks = pair & 7;
        int arr = pair >> 3;
        int l = threadIdx.x & 63;
        const float* Ws[6] = {W0, W1, W2, W3, W4, W5};
        const float* W = Ws[arr];
        bool use_lo = (ks >= 4);
        int kb = (ks & 3) * 32 + (l >> 4) * 8;
        uint4* out = Bf + (size_t)arr * 4096;
        #pragma unroll
        for (int ot = 0; ot < 8; ++ot) {
            int o = ot * 16 + (l & 15);
            u32 h[8];
            #pragma unroll
            for (int i = 0; i < 8; ++i) {
                float v = W[o * 128 + kb + i];
                __half hi = __float2half(v);
                if (use_lo) {
                    float rem = v - __half2float(hi);
                    __half lo = __float2half(rem);
                    h[i] = *(u16*)&lo;
                } else {
                    h[i] = *(u16*)&hi;
                }
            }
            uint4 u;
            u.x = h[0] | (h[1] << 16);
            u.y = h[2] | (h[3] << 16);
            u.z = h[4] | (h[5] << 16);
            u.w = h[6] | (h[7] << 16);
            out[(ks * 8 + ot) * 64 + l] = u;
        }
    } else {
        int e = (blk - PX - PW) * 256 + threadIdx.x;
        if (e < E) atomicAdd(&cnt[dst[e]], 1);
    }
}

// ---------------------------------------------- scan pass A: per-block sums
__global__ void scanA_kernel(const int* __restrict__ cnt, int* __restrict__ bsum, int n) {
    __shared__ int ws[4];
    int b = blockIdx.x, t = threadIdx.x;
    int base = b * SCHUNK + t * 8;
    int s = 0;
    #pragma unroll
    for (int k = 0; k < 8; ++k) {
        int i = base + k;
        s += (i < n) ? cnt[i] : 0;
    }
    #pragma unroll
    for (int off = 32; off >= 1; off >>= 1) s += __shfl_xor(s, off, 64);
    int w = t >> 6, lane = t & 63;
    if (lane == 0) ws[w] = s;
    __syncthreads();
    if (t == 0) bsum[b] = ws[0] + ws[1] + ws[2] + ws[3];
}

// ------------ scan pass C: block offset from bsum (in-wave) + local scan
__global__ void scanC_kernel(const int* __restrict__ cnt, const int* __restrict__ bsum,
                             int NB, int* __restrict__ rp, float* __restrict__ dinv, int n) {
    __shared__ int ws[4];
    __shared__ int base_s;
    int b = blockIdx.x, t = threadIdx.x;
    if (t < 64) {
        int v = (t < NB) ? bsum[t] : 0;
        int pre = (t < b) ? v : 0;
        #pragma unroll
        for (int off = 32; off >= 1; off >>= 1) pre += __shfl_xor(pre, off, 64);
        if (t == 0) base_s = pre;
        if (b == 0) {
            int tot = v;
            #pragma unroll
            for (int off = 32; off >= 1; off >>= 1) tot += __shfl_xor(tot, off, 64);
            if (t == 0) rp[n] = tot;
        }
    }
    __syncthreads();
    int boff = base_s;
    int base = b * SCHUNK + t * 8;
    int v[8];
    int ts = 0;
    #pragma unroll
    for (int k = 0; k < 8; ++k) {
        int i = base + k;
        v[k] = (i < n) ? cnt[i] : 0;
        ts += v[k];
    }
    int w = t >> 6, lane = t & 63;
    int x = ts;
    #pragma unroll
    for (int off = 1; off < 64; off <<= 1) {
        int y = __shfl_up(x, off, 64);
        if (lane >= off) x += y;
    }
    if (lane == 63) ws[w] = x;
    __syncthreads();
    int woff = 0;
    #pragma unroll
    for (int q = 0; q < 4; ++q) woff += (q < w) ? ws[q] : 0;
    int run = boff + woff + (x - ts);
    #pragma unroll
    for (int k = 0; k < 8; ++k) {
        int i = base + k;
        if (i < n) {
            rp[i] = run;
            dinv[i] = 1.0f / (float)max(v[k], 1);
        }
        run += v[k];
    }
}

// ==================================== fused CSR scatter + graph range bounds
__global__ void scatter_bounds(const int* __restrict__ src, const int* __restrict__ dst,
                               const int* __restrict__ rp, int* __restrict__ cursor,
                               int* __restrict__ esrc, int E, int SC,
                               const int* __restrict__ batch, int* __restrict__ gstart,
                               int n, int g) {
    int blk = blockIdx.x;
    if (blk < SC) {
        int e = blk * 256 + threadIdx.x;
        if (e < E) {
            int d = dst[e];
            int pos = rp[d] + atomicAdd(&cursor[d], 1);
            esrc[pos] = src[e];
        }
    } else {
        int i = (blk - SC) * 256 + threadIdx.x;
        if (i >= n) return;
        int b = batch[i];
        int pb = (i == 0) ? -1 : batch[i - 1];
        for (int q = pb + 1; q <= b; ++q) gstart[q] = i;
        if (i == n - 1) {
            for (int q = b + 1; q <= g; ++q) gstart[q] = n;
        }
    }
}

// --------------------------------------------------- mean aggregation (CSR)
// 16 lanes per node; lane covers 8 fp16 features (uint4 = 16B); x8 edge unroll.
__device__ inline void add8(float* a, uint4 u) {
    float2 f0 = __half22float2(*(__half2*)&u.x);
    float2 f1 = __half22float2(*(__half2*)&u.y);
    float2 f2 = __half22float2(*(__half2*)&u.z);
    float2 f3 = __half22float2(*(__half2*)&u.w);
    a[0] += f0.x; a[1] += f0.y; a[2] += f1.x; a[3] += f1.y;
    a[4] += f2.x; a[5] += f2.y; a[6] += f3.x; a[7] += f3.y;
}

__global__ void agg_kernel(const u16* __restrict__ h16,
                           const int* __restrict__ rp, const int* __restrict__ esrc,
                           const float* __restrict__ dinv,
                           u16* __restrict__ agg16, int n_nodes) {
    int node = blockIdx.x * 16 + (threadIdx.x >> 4);
    if (node >= n_nodes) return;
    int lane = threadIdx.x & 15;
    int f = lane * 8;
    int s0 = rp[node], s1 = rp[node + 1];
    float a0[8] = {0, 0, 0, 0, 0, 0, 0, 0};
    float a1[8] = {0, 0, 0, 0, 0, 0, 0, 0};
    float a2[8] = {0, 0, 0, 0, 0, 0, 0, 0};
    float a3[8] = {0, 0, 0, 0, 0, 0, 0, 0};
    int j = s0;
    for (; j + 8 <= s1; j += 8) {
        int i0 = esrc[j],     i1 = esrc[j + 1], i2 = esrc[j + 2], i3 = esrc[j + 3];
        int i4 = esrc[j + 4], i5 = esrc[j + 5], i6 = esrc[j + 6], i7 = esrc[j + 7];
        uint4 u0 = *(const uint4*)(h16 + (size_t)i0 * FH + f);
        uint4 u1 = *(const uint4*)(h16 + (size_t)i1 * FH + f);
        uint4 u2 = *(const uint4*)(h16 + (size_t)i2 * FH + f);
        uint4 u3 = *(const uint4*)(h16 + (size_t)i3 * FH + f);
        uint4 u4 = *(const uint4*)(h16 + (size_t)i4 * FH + f);
        uint4 u5 = *(const uint4*)(h16 + (size_t)i5 * FH + f);
        uint4 u6 = *(const uint4*)(h16 + (size_t)i6 * FH + f);
        uint4 u7 = *(const uint4*)(h16 + (size_t)i7 * FH + f);
        add8(a0, u0); add8(a1, u1); add8(a2, u2); add8(a3, u3);
        add8(a0, u4); add8(a1, u5); add8(a2, u6); add8(a3, u7);
    }
    if (j + 4 <= s1) {
        int i0 = esrc[j], i1 = esrc[j + 1], i2 = esrc[j + 2], i3 = esrc[j + 3];
        uint4 u0 = *(const uint4*)(h16 + (size_t)i0 * FH + f);
        uint4 u1 = *(const uint4*)(h16 + (size_t)i1 * FH + f);
        uint4 u2 = *(const uint4*)(h16 + (size_t)i2 * FH + f);
        uint4 u3 = *(const uint4*)(h16 + (size_t)i3 * FH + f);
        add8(a0, u0); add8(a1, u1); add8(a2, u2); add8(a3, u3);
        j += 4;
    }
    for (; j < s1; ++j) {
        uint4 u0 = *(const uint4*)(h16 + (size_t)esrc[j] * FH + f);
        add8(a0, u0);
    }
    float di = dinv[node];
    u32 oh[8];
    #pragma unroll
    for (int i = 0; i < 8; ++i) {
        __half hv = __float2half((a0[i] + a1[i] + a2[i] + a3[i]) * di);
        oh[i] = *(u16*)&hv;
    }
    uint4 w;
    w.x = oh[0] | (oh[1] << 16);
    w.y = oh[2] | (oh[3] << 16);
    w.z = oh[4] | (oh[5] << 16);
    w.w = oh[6] | (oh[7] << 16);
    *(uint4*)(agg16 + (size_t)node * FH + f) = w;
}

// ----------------------------------------------------------- MFMA SAGE GEMM
// Exact R11 structure (best measured): 256 thr / 4 waves, 192-node tile,
// per-source async global_load_lds B staging (64 KB), A prefetch in regs,
// pure-LDS K-loop (hi then lo phase).
__global__ __launch_bounds__(256, 2)
void mfma_gemm(const u16* __restrict__ A1, const u16* __restrict__ A2,
               const uint4* __restrict__ Bf1, const uint4* __restrict__ Bf2,
               const float* __restrict__ bias, u16* __restrict__ out16,
               int do_relu) {
    __shared__ uint4 Bl[4096];  // 64 KB
    int tid = threadIdx.x;
    int l = tid & 63;
    int wv = tid >> 6;
    int bn0 = blockIdx.x * 192 + wv * 48;
    int m = l & 15, q = l >> 4;

    f4frag acc[3][8];
    #pragma unroll
    for (int i = 0; i < 3; ++i)
        #pragma unroll
        for (int o = 0; o < 8; ++o)
            acc[i][o] = (f4frag){0.f, 0.f, 0.f, 0.f};

    #pragma unroll
    for (int p = 0; p < 2; ++p) {
        const u16* P = p ? A2 : A1;
        const uint4* Bf = p ? Bf2 : Bf1;

        // A prefetch (registers; in flight across the barrier)
        f16frag Af[3][4];
        #pragma unroll
        for (int nt = 0; nt < 3; ++nt)
            #pragma unroll
            for (int s = 0; s < 4; ++s)
                Af[nt][s] = *(const f16frag*)(P + (size_t)(bn0 + nt * 16 + m) * FH + s * 32 + q * 8);

        __syncthreads();   // all waves done with previous source's Bl

        #pragma unroll
        for (int u = 0; u < 16; ++u)
            async_copy16(Bf + (size_t)u * 256 + wv * 64 + l,
                         &Bl[u * 256 + wv * 64]);
        __syncthreads();   // drains vmcnt -> staging complete

        #pragma unroll
        for (int s = 0; s < 4; ++s) {
            {
                f16frag B[8];
                #pragma unroll
                for (int ot = 0; ot < 8; ++ot)
                    B[ot] = *(const f16frag*)&Bl[(size_t)(s * 8 + ot) * 64 + l];
                #pragma unroll
                for (int ot = 0; ot < 8; ++ot)
                    #pragma unroll
                    for (int nt = 0; nt < 3; ++nt)
                        acc[nt][ot] = __builtin_amdgcn_mfma_f32_16x16x32_f16(Af[nt][s], B[ot], acc[nt][ot], 0, 0, 0);
            }
            {
                f16frag B[8];
                #pragma unroll
                for (int ot = 0; ot < 8; ++ot)
                    B[ot] = *(const f16frag*)&Bl[(size_t)((s + 4) * 8 + ot) * 64 + l];
                #pragma unroll
                for (int ot = 0; ot < 8; ++ot)
                    #pragma unroll
                    for (int nt = 0; nt < 3; ++nt)
                        acc[nt][ot] = __builtin_amdgcn_mfma_f32_16x16x32_f16(Af[nt][s], B[ot], acc[nt][ot], 0, 0, 0);
            }
        }
    }

    #pragma unroll
    for (int nt = 0; nt < 3; ++nt)
        #pragma unroll
        for (int r = 0; r < 4; ++r) {
            int node = bn0 + nt * 16 + q * 4 + r;
            #pragma unroll
            for (int ot = 0; ot < 8; ++ot) {
                float v = acc[nt][ot][r] + bias[ot * 16 + m];
                if (do_relu) v = fmaxf(v, 0.f);
                __half hv = __float2half(v);
                out16[(size_t)node * FH + ot * 16 + m] = *(u16*)&hv;
            }
        }
}

// --------------------------------------------- fused pooling + final linear
__global__ __launch_bounds__(256, 2)
void pool_final(const u16* __restrict__ h16, const int* __restrict__ gstart,
                const float* __restrict__ Wlin, const float* __restrict__ blin,
                float* __restrict__ out) {
    __shared__ float smax[16][FH];
    __shared__ float ssum[16][FH];
    __shared__ float pr[2 * FH];
    int g = blockIdx.x;
    int tid = threadIdx.x;
    int way = tid >> 4;
    int lane = tid & 15;
    int f = lane * 8;
    int s = gstart[g], e = gstart[g + 1];

    float mx[8], sm[8];
    #pragma unroll
    for (int i = 0; i < 8; ++i) { mx[i] = -INFINITY; sm[i] = 0.f; }
    for (int n = s + way; n < e; n += 16) {
        uint4 u = *(const uint4*)(h16 + (size_t)n * FH + f);
        float2 f0 = __half22float2(*(__half2*)&u.x);
        float2 f1 = __half22float2(*(__half2*)&u.y);
        float2 f2 = __half22float2(*(__half2*)&u.z);
        float2 f3 = __half22float2(*(__half2*)&u.w);
        float v[8] = {f0.x, f0.y, f1.x, f1.y, f2.x, f2.y, f3.x, f3.y};
        #pragma unroll
        for (int i = 0; i < 8; ++i) {
            mx[i] = fmaxf(mx[i], v[i]);
            sm[i] += v[i];
        }
    }
    #pragma unroll
    for (int i = 0; i < 8; ++i) {
        smax[way][f + i] = mx[i];
        ssum[way][f + i] = sm[i];
    }
    __syncthreads();
    int c = e - s;
    if (tid < FH) {
        float m2 = -INFINITY, s2 = 0.f;
        #pragma unroll
        for (int w2 = 0; w2 < 16; ++w2) {
            m2 = fmaxf(m2, smax[w2][tid]);
            s2 += ssum[w2][tid];
        }
        pr[tid] = (c > 0) ? m2 : 0.f;
        pr[FH + tid] = s2 / (float)max(c, 1);
    }
    __syncthreads();
    int o = tid;
    const float4* wr = (const float4*)(Wlin + (size_t)o * (2 * FH));
    float acc = 0.f;
    #pragma unroll
    for (int j = 0; j < (2 * FH) / 4; ++j) {
        float4 wv = wr[j];
        acc += wv.x * pr[j * 4 + 0] + wv.y * pr[j * 4 + 1] +
               wv.z * pr[j * 4 + 2] + wv.w * pr[j * 4 + 3];
    }
    out[(size_t)g * OUTD + o] = acc + blin[o];
}

extern "C" void kernel_launch(void* const* d_in, const int* in_sizes, int n_in,
                              void* d_out, int out_size, void* d_ws, size_t ws_size,
                              hipStream_t stream) {
    const float* x     = (const float*)d_in[0];
    const int*   ei    = (const int*)d_in[1];
    const int*   batch = (const int*)d_in[2];
    const float* W1l = (const float*)d_in[3];
    const float* b1  = (const float*)d_in[4];
    const float* W1r = (const float*)d_in[5];
    const float* W2l = (const float*)d_in[6];
    const float* b2  = (const float*)d_in[7];
    const float* W2r = (const float*)d_in[8];
    const float* W3l = (const float*)d_in[9];
    const float* b3  = (const float*)d_in[10];
    const float* W3r = (const float*)d_in[11];
    const float* Wlin = (const float*)d_in[12];
    const float* blin = (const float*)d_in[13];
    float* out = (float*)d_out;

    const int E = in_sizes[1] / 2;
    const int N = in_sizes[2];
    const int G = out_size / OUTD;
    const int* src = ei;
    const int* dst = ei + E;
    const int NB = (N + SCHUNK - 1) / SCHUNK;
    const int GB = (N + 191) / 192;
    const int NP = GB * 192;

    // ---- workspace carve-up ----
    char* w = (char*)d_ws;
    auto alloc = [&](size_t bytes) {
        void* p = (void*)w;
        w += (bytes + 255) & ~(size_t)255;
        return p;
    };
    int*   cnt    = (int*)alloc((size_t)2 * N * sizeof(int));
    int*   cursor = cnt + N;
    int*   rp     = (int*)alloc((size_t)(N + 1) * sizeof(int));
    int*   esrc   = (int*)alloc((size_t)E * sizeof(int));
    int*   gstart = (int*)alloc((size_t)(G + 1) * sizeof(int));
    float* dinv   = (float*)alloc((size_t)N * sizeof(float));
    int*   bsum   = (int*)alloc(64 * sizeof(int));
    u16*   x16    = (u16*)alloc((size_t)NP * FH * sizeof(u16));
    u16*   agg16  = (u16*)alloc((size_t)NP * FH * sizeof(u16));
    u16*   hA16   = (u16*)alloc((size_t)NP * FH * sizeof(u16));
    u16*   hB16   = (u16*)alloc((size_t)NP * FH * sizeof(u16));
    uint4* BF     = (uint4*)alloc((size_t)6 * 4096 * sizeof(uint4));
    (void)ws_size;

    // ---- fused prep (prep_x | prep_w | hist) ----
    hipMemsetAsync(cnt, 0, (size_t)2 * N * sizeof(int), stream);
    const int n4 = N * 32;
    const int PX = (n4 + 255) / 256;
    const int PW = 12;
    const int PH = (E + 255) / 256;
    prep_all<<<PX + PW + PH, 256, 0, stream>>>(x, x16, n4, PX,
                                               W1l, W1r, W2l, W2r, W3l, W3r, BF, PW,
                                               dst, cnt, E);

    // ---- CSR build ----
    scanA_kernel<<<NB, 256, 0, stream>>>(cnt, bsum, N);
    scanC_kernel<<<NB, 256, 0, stream>>>(cnt, bsum, NB, rp, dinv, N);
    const int SC = (E + 255) / 256;
    const int GBND = (N + 255) / 256;
    scatter_bounds<<<SC + GBND, 256, 0, stream>>>(src, dst, rp, cursor, esrc, E, SC,
                                                  batch, gstart, N, G);

    const int agg_grid = (N + 15) / 16;

    // ---- layer 1 ----
    agg_kernel<<<agg_grid, 256, 0, stream>>>(x16, rp, esrc, dinv, agg16, N);
    mfma_gemm<<<GB, 256, 0, stream>>>(agg16, x16, BF + 0 * 4096, BF + 1 * 4096, b1, hA16, 1);
    // ---- layer 2 ----
    agg_kernel<<<agg_grid, 256, 0, stream>>>(hA16, rp, esrc, dinv, agg16, N);
    mfma_gemm<<<GB, 256, 0, stream>>>(agg16, hA16, BF + 2 * 4096, BF + 3 * 4096, b2, hB16, 1);
    // ---- layer 3 ----
    agg_kernel<<<agg_grid, 256, 0, stream>>>(hB16, rp, esrc, dinv, agg16, N);
    mfma_gemm<<<GB, 256, 0, stream>>>(agg16, hB16, BF + 4 * 4096, BF + 5 * 4096, b3, hA16, 0);

    // ---- fused pool + head ----
    pool_final<<<G, 256, 0, stream>>>(hA16, gstart, Wlin, blin, out);
}